// Round 3
// 3103.836 us; speedup vs baseline: 1.5539x; 1.5539x over previous
//
#include <hip/hip_runtime.h>

#define HN 48
#define WN 48
#define CIN_ 256
#define H_ 192
#define W_ 192
#define COUT_ 256

#define PROJ_N (256 * 512)

#define DOT4(a, xv, wv) a += xv.x*wv.x + xv.y*wv.y + xv.z*wv.z + xv.w*wv.w

typedef __attribute__((ext_vector_type(8))) short bf16x8;   // 8 bf16 (MFMA A/B frag)
typedef __attribute__((ext_vector_type(4))) float f32x4;    // MFMA C/D frag

__device__ __forceinline__ unsigned short f2b(float f) {    // fp32 -> bf16 RNE
    unsigned int u = __float_as_uint(f);
    u = u + 0x7FFFu + ((u >> 16) & 1u);
    return (unsigned short)(u >> 16);
}
__device__ __forceinline__ float b2f(unsigned short h) {
    return __uint_as_float(((unsigned int)h) << 16);
}

// One-time proj weight split: w = hi(bf16) + lo(bf16). The att->proj path is NOT
// relu-amplified, so 3-MFMA 2-way split (~2^-17 rel) adds only ~1e-5 to y.
// ws layout (ushort): proj_h @0, proj_l @PROJ_N  (524,288 B)
__global__ __launch_bounds__(256) void prep_weights(const float* __restrict__ proj_w,
                                                    unsigned short* __restrict__ ws) {
    const int idx = blockIdx.x * 256 + threadIdx.x;
    if (idx < PROJ_N) {
        const float v = proj_w[idx];
        const unsigned short h = f2b(v);
        ws[idx] = h;
        ws[PROJ_N + idx] = f2b(v - b2f(h));
    }
}

// One workgroup (256 threads = 4 waves) per 4x4 window.
//   A : load x window -> LDS xs[pix][c] (fp32, pad 260)  [baseline-identical]
//   4 passes x 8 heads:
//     B : qkv GEMM in fp32 VALU, arithmetic per-channel BIT-IDENTICAL to the
//         passing baseline (same DOT4 tree, c ascending). Weights now come from a
//         double-buffered LDS tile (reg-staged, 16-col chunks) instead of global
//         -> removes the L2-latency serialization that dominated the baseline.
//         (Bit-compat matters: the relu in C amplifies qs perturbations ~1e4x on
//         borderline logits; pinning qs bits pins the known-passing error 4.9e-4.)
//     B2: 5x5/pad2 avg-pool within window (fp32, verbatim)
//     C : linear attention (fp32 butterfly, verbatim), att -> bf16 hi/lo frags
//     D : proj partial GEMM on matrix cores (3-MFMA 2-way split)  [~16x fewer
//         VALU cycles than the baseline's scalar phase D]
//   epilogue: transpose pacc through LDS, BN, coalesced float4 store
__global__ __launch_bounds__(256, 2)
void wmsa_fused(const float* __restrict__ x, const float* __restrict__ qkv_w,
                const unsigned short* __restrict__ wp_h, const unsigned short* __restrict__ wp_l,
                const float* __restrict__ bn_g, const float* __restrict__ bn_b,
                const float* __restrict__ bn_m, const float* __restrict__ bn_v,
                float* __restrict__ y)
{
    __shared__ __align__(16) float xs[16 * 260];          // 16,640 B
    __shared__ __align__(16) float wt[2][192 * 16];       // 24,576 B  qkv weight chunks (dbuf)
    __shared__ __align__(16) float qs[384 * 16];          // 24,576 B  qkv + pooled
    __shared__ __align__(16) unsigned short af_hi[2048];  //  4,096 B  att frags hi
    __shared__ __align__(16) unsigned short af_lo[2048];  //  4,096 B  att frags lo
                                                          // total 73,984 B -> 2 WG/CU

    const int t = threadIdx.x;
    const int bid = blockIdx.x;
    // XCD swizzle: 8 consecutive windows -> same XCD (bid%8)
    const int win = (bid % 1152) * 8 + (bid / 1152);
    const int b = win / (HN * WN);
    const int rem = win % (HN * WN);
    const int hn = rem / WN, wn = rem % WN;
    const int h0 = hn * 4, w0 = wn * 4;

    // ---- Phase A: load x window (256 ch x 16 pix), fp32 [baseline-identical] ----
    for (int idx = t; idx < 1024; idx += 256) {
        const int c = idx >> 2, i = idx & 3;
        const size_t ea = ((size_t)(b * CIN_ + c) * H_ + (h0 + i)) * (size_t)W_ + w0;
        const float4 r = *reinterpret_cast<const float4*>(x + ea);  // 16B, aligned
        xs[(i * 4 + 0) * 260 + c] = r.x;
        xs[(i * 4 + 1) * 260 + c] = r.y;
        xs[(i * 4 + 2) * 260 + c] = r.z;
        xs[(i * 4 + 3) * 260 + c] = r.w;
    }

    const int og = t >> 4;     // 0..15
    const int pix = t & 15;    // 0..15
    const int lane = t & 63;
    const int wv = t >> 6;       // wave 0..3
    const int lrow = lane & 15;  // MFMA row/col lane
    const int lk = lane >> 4;    // k-subblock 0..3

    f32x4 pacc[4];               // proj accumulators, live across all passes
#pragma unroll
    for (int i = 0; i < 4; ++i) pacc[i] = (f32x4){0.f, 0.f, 0.f, 0.f};

    // reg-stage slots for the weight tile: 768 float4 slots / 256 threads = 3 each
    const int s0 = t, s1 = t + 256, s2 = t + 512;   // slot = row*4 + cq
    float4 stg0, stg1, stg2;

    __syncthreads();

    for (int pass = 0; pass < 4; ++pass) {
        // ---- Phase B: qkv GEMM, fp32 VALU, weights via LDS chunks of 16 cols ----
        float a[12];
#pragma unroll
        for (int r = 0; r < 12; ++r) a[r] = 0.f;

        // prologue: stage chunk 0 into buf 0
        {
            const float* gw = qkv_w + (size_t)pass * 192 * 256;
            stg0 = *reinterpret_cast<const float4*>(gw + (s0 >> 2) * 256 + (s0 & 3) * 4);
            stg1 = *reinterpret_cast<const float4*>(gw + (s1 >> 2) * 256 + (s1 & 3) * 4);
            stg2 = *reinterpret_cast<const float4*>(gw + (s2 >> 2) * 256 + (s2 & 3) * 4);
            *reinterpret_cast<float4*>(&wt[0][s0 * 4]) = stg0;
            *reinterpret_cast<float4*>(&wt[0][s1 * 4]) = stg1;
            *reinterpret_cast<float4*>(&wt[0][s2 * 4]) = stg2;
        }
        __syncthreads();

        for (int cc = 0; cc < 16; ++cc) {
            const int buf = cc & 1;
            // prefetch next chunk into registers (hidden under compute)
            if (cc < 15) {
                const float* gw = qkv_w + (size_t)pass * 192 * 256 + (cc + 1) * 16;
                stg0 = *reinterpret_cast<const float4*>(gw + (s0 >> 2) * 256 + (s0 & 3) * 4);
                stg1 = *reinterpret_cast<const float4*>(gw + (s1 >> 2) * 256 + (s1 & 3) * 4);
                stg2 = *reinterpret_cast<const float4*>(gw + (s2 >> 2) * 256 + (s2 & 3) * 4);
            }
            // compute this chunk: per-channel chains accumulate over c ascending,
            // identical statement tree to baseline -> bit-identical qs
            const float* xrow = &xs[pix * 260 + cc * 16];
#pragma unroll
            for (int c4 = 0; c4 < 4; ++c4) {
                const float4 xv = *reinterpret_cast<const float4*>(&xrow[c4 * 4]);
#pragma unroll
                for (int k = 0; k < 3; ++k) {
                    const int o0 = og * 12 + k * 4;
                    const float4 wv0 = *reinterpret_cast<const float4*>(&wt[buf][(o0 + 0) * 16 + c4 * 4]);
                    const float4 wv1 = *reinterpret_cast<const float4*>(&wt[buf][(o0 + 1) * 16 + c4 * 4]);
                    const float4 wv2 = *reinterpret_cast<const float4*>(&wt[buf][(o0 + 2) * 16 + c4 * 4]);
                    const float4 wv3 = *reinterpret_cast<const float4*>(&wt[buf][(o0 + 3) * 16 + c4 * 4]);
                    DOT4(a[k * 4 + 0], xv, wv0);
                    DOT4(a[k * 4 + 1], xv, wv1);
                    DOT4(a[k * 4 + 2], xv, wv2);
                    DOT4(a[k * 4 + 3], xv, wv3);
                }
            }
            // publish next chunk (other buffer — safe while peers finish this one)
            if (cc < 15) {
                *reinterpret_cast<float4*>(&wt[buf ^ 1][s0 * 4]) = stg0;
                *reinterpret_cast<float4*>(&wt[buf ^ 1][s1 * 4]) = stg1;
                *reinterpret_cast<float4*>(&wt[buf ^ 1][s2 * 4]) = stg2;
            }
            __syncthreads();
        }
        // write qs[ch][pix]
#pragma unroll
        for (int k = 0; k < 3; ++k) {
            const int o0 = og * 12 + k * 4;
            qs[(o0 + 0) * 16 + pix] = a[k * 4 + 0];
            qs[(o0 + 1) * 16 + pix] = a[k * 4 + 1];
            qs[(o0 + 2) * 16 + pix] = a[k * 4 + 2];
            qs[(o0 + 3) * 16 + pix] = a[k * 4 + 3];
        }
        __syncthreads();

        // ---- Phase B2: 5x5 avg-pool (pad 2) within the 4x4 window, 192 ch ----
        if (t < 192) {
            const float4* sr = reinterpret_cast<const float4*>(&qs[t * 16]);
            const float4 r0 = sr[0], r1 = sr[1], r2 = sr[2], r3 = sr[3];
            float col[4], tmp0[4], tmp3[4];
            {
                const float c0 = r0.x + r1.x + r2.x + r3.x;
                const float c1 = r0.y + r1.y + r2.y + r3.y;
                const float c2 = r0.z + r1.z + r2.z + r3.z;
                const float c3 = r0.w + r1.w + r2.w + r3.w;
                col[0] = c0; col[1] = c1; col[2] = c2; col[3] = c3;
                tmp0[0] = c0 - r3.x; tmp0[1] = c1 - r3.y; tmp0[2] = c2 - r3.z; tmp0[3] = c3 - r3.w;
                tmp3[0] = c0 - r0.x; tmp3[1] = c1 - r0.y; tmp3[2] = c2 - r0.z; tmp3[3] = c3 - r0.w;
            }
            float4* pr = reinterpret_cast<float4*>(&qs[(192 + t) * 16]);
            const float k25 = 1.f / 25.f;
#pragma unroll
            for (int i = 0; i < 4; ++i) {
                const float* tr = (i == 0) ? tmp0 : ((i == 3) ? tmp3 : col);
                const float hs = tr[0] + tr[1] + tr[2] + tr[3];
                float4 o;
                o.x = (hs - tr[3]) * k25;
                o.y = hs * k25;
                o.z = hs * k25;
                o.w = (hs - tr[0]) * k25;
                pr[i] = o;
            }
        }
        __syncthreads();

        // ---- Phase C: linear attention (fp32, verbatim), att -> bf16 hi/lo frags ----
        {
            const int grp = t >> 4;        // 0..15 (8 direct + 8 pooled)
            const int l = t & 15;          // pixel
            const int base = (grp < 8) ? (grp * 24 * 16) : ((192 + (grp - 8) * 24) * 16);

            float qd[8], kd[8], vm[8];
#pragma unroll
            for (int d = 0; d < 8; ++d) qd[d] = fmaxf(0.f, qs[base + d * 16 + l]);
#pragma unroll
            for (int d = 0; d < 8; ++d) kd[d] = fmaxf(0.f, qs[base + (8 + d) * 16 + l]);
#pragma unroll
            for (int m = 0; m < 8; ++m) vm[m] = qs[base + (16 + m) * 16 + l];

            float kv[8][9];
#pragma unroll
            for (int d = 0; d < 8; ++d) {
#pragma unroll
                for (int m = 0; m < 8; ++m) kv[d][m] = kd[d] * vm[m];
                kv[d][8] = kd[d];          // v[:,8] == 1 (pad)
            }
#pragma unroll
            for (int off = 1; off <= 8; off <<= 1)
#pragma unroll
                for (int d = 0; d < 8; ++d)
#pragma unroll
                    for (int m = 0; m < 9; ++m)
                        kv[d][m] += __shfl_xor(kv[d][m], off, 64);

            float o8 = 0.f;
#pragma unroll
            for (int d = 0; d < 8; ++d) o8 += qd[d] * kv[d][8];
            const float den = 1.f / (o8 + 1e-15f);

            // att frag layout: elem = (kblk*16 + pix)*8 + j; kblk = grp, j = m
            bf16x8 sh, sl;
#pragma unroll
            for (int m = 0; m < 8; ++m) {
                float om = 0.f;
#pragma unroll
                for (int d = 0; d < 8; ++d) om += qd[d] * kv[d][m];
                const float vvv = om * den;
                const unsigned short h = f2b(vvv);
                sh[m] = (short)h;
                sl[m] = (short)f2b(vvv - b2f(h));
            }
            *reinterpret_cast<bf16x8*>(&af_hi[t * 8]) = sh;
            *reinterpret_cast<bf16x8*>(&af_lo[t * 8]) = sl;
        }
        __syncthreads();

        // ---- Phase D: proj partial GEMM via MFMA.  Wave wv owns oc-tiles wv*4+{0..3} ----
        {
#pragma unroll
            for (int s = 0; s < 4; ++s) {
                const int u = ((s * 4 + lk) * 16 + lrow) * 8;
                const bf16x8 bh = *reinterpret_cast<const bf16x8*>(&af_hi[u]);
                const bf16x8 bl = *reinterpret_cast<const bf16x8*>(&af_lo[u]);
                // local k 0..63 -> direct cols pass*64+k ; 64..127 -> pooled 256+pass*64+(k-64)
                const int colbase = ((s < 2) ? (pass * 64 + s * 32)
                                             : (256 + pass * 64 + (s - 2) * 32)) + lk * 8;
#pragma unroll
                for (int tt = 0; tt < 4; ++tt) {
                    const int row = (wv * 4 + tt) * 16 + lrow;
                    const bf16x8 ah = *reinterpret_cast<const bf16x8*>(wp_h + (size_t)row * 512 + colbase);
                    const bf16x8 al = *reinterpret_cast<const bf16x8*>(wp_l + (size_t)row * 512 + colbase);
                    pacc[tt] = __builtin_amdgcn_mfma_f32_16x16x32_bf16(ah, bh, pacc[tt], 0, 0, 0);
                    pacc[tt] = __builtin_amdgcn_mfma_f32_16x16x32_bf16(ah, bl, pacc[tt], 0, 0, 0);
                    pacc[tt] = __builtin_amdgcn_mfma_f32_16x16x32_bf16(al, bh, pacc[tt], 0, 0, 0);
                }
            }
        }
        __syncthreads();
    }

    // ---- Epilogue: transpose pacc through LDS (qs is free), BN, coalesced stores ----
#pragma unroll
    for (int tt = 0; tt < 4; ++tt) {
        const int c0 = (wv * 4 + tt) * 16 + lk * 4;
#pragma unroll
        for (int r = 0; r < 4; ++r)
            qs[(c0 + r) * 16 + lrow] = pacc[tt][r];
    }
    __syncthreads();
    {
        const int oc = t;
        const float inv = bn_g[oc] * __frsqrt_rn(bn_v[oc] + 1e-5f);
        const float bet2 = bn_b[oc] - bn_m[oc] * inv;
        const float* rowp = &qs[oc * 16];
#pragma unroll
        for (int i = 0; i < 4; ++i) {
            float4 s4;
            s4.x = rowp[i * 4 + 0] * inv + bet2;
            s4.y = rowp[i * 4 + 1] * inv + bet2;
            s4.z = rowp[i * 4 + 2] * inv + bet2;
            s4.w = rowp[i * 4 + 3] * inv + bet2;
            const size_t ea = ((size_t)(b * COUT_ + oc) * H_ + (h0 + i)) * (size_t)W_ + w0;
            *reinterpret_cast<float4*>(y + ea) = s4;    // 16B store, aligned
        }
    }
}

extern "C" void kernel_launch(void* const* d_in, const int* in_sizes, int n_in,
                              void* d_out, int out_size, void* d_ws, size_t ws_size,
                              hipStream_t stream) {
    const float* x      = (const float*)d_in[0];
    const float* qkv_w  = (const float*)d_in[1];
    const float* proj_w = (const float*)d_in[2];
    const float* bn_g   = (const float*)d_in[3];
    const float* bn_b   = (const float*)d_in[4];
    const float* bn_m   = (const float*)d_in[5];
    const float* bn_v   = (const float*)d_in[6];
    float* y = (float*)d_out;

    unsigned short* ws = (unsigned short*)d_ws;   // needs 524,288 B
    prep_weights<<<dim3(512), dim3(256), 0, stream>>>(proj_w, ws);
    wmsa_fused<<<dim3(9216), dim3(256), 0, stream>>>(
        x, qkv_w, ws, ws + PROJ_N,
        bn_g, bn_b, bn_m, bn_v, y);
}

// Round 4
// 2807.103 us; speedup vs baseline: 1.7182x; 1.1057x over previous
//
#include <hip/hip_runtime.h>

#define HN 48
#define WN 48
#define CIN_ 256
#define H_ 192
#define W_ 192
#define COUT_ 256

#define PROJ_N (256 * 512)

#define DOT4(a, xv, wv) a += xv.x*wv.x + xv.y*wv.y + xv.z*wv.z + xv.w*wv.w

typedef __attribute__((ext_vector_type(8))) short bf16x8;   // 8 bf16 (MFMA A/B frag)
typedef __attribute__((ext_vector_type(4))) float f32x4;    // MFMA C/D frag

__device__ __forceinline__ unsigned short f2b(float f) {    // fp32 -> bf16 RNE
    unsigned int u = __float_as_uint(f);
    u = u + 0x7FFFu + ((u >> 16) & 1u);
    return (unsigned short)(u >> 16);
}
__device__ __forceinline__ float b2f(unsigned short h) {
    return __uint_as_float(((unsigned int)h) << 16);
}

// One-time proj weight split: w = hi(bf16) + lo(bf16). The att->proj path is NOT
// relu-amplified, so 3-MFMA 2-way split (~2^-17 rel) adds only ~1e-5 to y.
// ws layout (ushort): proj_h @0, proj_l @PROJ_N  (524,288 B)
__global__ __launch_bounds__(256) void prep_weights(const float* __restrict__ proj_w,
                                                    unsigned short* __restrict__ ws) {
    const int idx = blockIdx.x * 256 + threadIdx.x;
    if (idx < PROJ_N) {
        const float v = proj_w[idx];
        const unsigned short h = f2b(v);
        ws[idx] = h;
        ws[PROJ_N + idx] = f2b(v - b2f(h));
    }
}

// One workgroup (256 threads = 4 waves) per 4x4 window.
//   A : load x window -> LDS xs[pix][c] (fp32, pad 260)
//   4 passes x 8 heads:
//     B : qkv GEMM in fp32 VALU, per-channel arithmetic BIT-IDENTICAL to the
//         passing baseline (same DOT4 tree, c ascending). Weights via
//         double-buffered LDS tile (reg-staged, 16-col chunks).
//         Channel->thread map is og-stride-16 (og + 16j), so a wave's 4 og-groups
//         read rows 64B apart -> 2-way bank alias (free) instead of the old
//         og*12 map whose 768B row stride aliased all 4 groups onto the same
//         banks (4-way conflict on 48 b128 reads/chunk = the 5.19e8 counter).
//     B2: 5x5/pad2 avg-pool within window (fp32, verbatim)
//     C : linear attention (fp32 butterfly, verbatim), att -> bf16 hi/lo frags
//     D : proj partial GEMM on matrix cores (3-MFMA 2-way split)
//   epilogue: transpose pacc through LDS, BN, coalesced float4 store
__global__ __launch_bounds__(256, 2)
void wmsa_fused(const float* __restrict__ x, const float* __restrict__ qkv_w,
                const unsigned short* __restrict__ wp_h, const unsigned short* __restrict__ wp_l,
                const float* __restrict__ bn_g, const float* __restrict__ bn_b,
                const float* __restrict__ bn_m, const float* __restrict__ bn_v,
                float* __restrict__ y)
{
    __shared__ __align__(16) float xs[16 * 260];          // 16,640 B
    __shared__ __align__(16) float wt[2][192 * 16];       // 24,576 B  qkv weight chunks (dbuf)
    __shared__ __align__(16) float qs[384 * 16];          // 24,576 B  qkv + pooled
    __shared__ __align__(16) unsigned short af_hi[2048];  //  4,096 B  att frags hi
    __shared__ __align__(16) unsigned short af_lo[2048];  //  4,096 B  att frags lo
                                                          // total 73,984 B -> 2 WG/CU

    const int t = threadIdx.x;
    const int bid = blockIdx.x;
    // XCD swizzle: 8 consecutive windows -> same XCD (bid%8)
    const int win = (bid % 1152) * 8 + (bid / 1152);
    const int b = win / (HN * WN);
    const int rem = win % (HN * WN);
    const int hn = rem / WN, wn = rem % WN;
    const int h0 = hn * 4, w0 = wn * 4;

    // ---- Phase A: load x window (256 ch x 16 pix), fp32 ----
    for (int idx = t; idx < 1024; idx += 256) {
        const int c = idx >> 2, i = idx & 3;
        const size_t ea = ((size_t)(b * CIN_ + c) * H_ + (h0 + i)) * (size_t)W_ + w0;
        const float4 r = *reinterpret_cast<const float4*>(x + ea);  // 16B, aligned
        xs[(i * 4 + 0) * 260 + c] = r.x;
        xs[(i * 4 + 1) * 260 + c] = r.y;
        xs[(i * 4 + 2) * 260 + c] = r.z;
        xs[(i * 4 + 3) * 260 + c] = r.w;
    }

    const int og = t >> 4;     // 0..15
    const int pix = t & 15;    // 0..15
    const int lane = t & 63;
    const int wv = t >> 6;       // wave 0..3
    const int lrow = lane & 15;  // MFMA row/col lane
    const int lk = lane >> 4;    // k-subblock 0..3

    f32x4 pacc[4];               // proj accumulators, live across all passes
#pragma unroll
    for (int i = 0; i < 4; ++i) pacc[i] = (f32x4){0.f, 0.f, 0.f, 0.f};

    // reg-stage slots for the weight tile: 768 float4 slots / 256 threads = 3 each
    const int s0 = t, s1 = t + 256, s2 = t + 512;   // slot = row*4 + cq
    float4 stg0, stg1, stg2;

    __syncthreads();

    for (int pass = 0; pass < 4; ++pass) {
        // ---- Phase B: qkv GEMM, fp32 VALU, weights via LDS chunks of 16 cols ----
        float a[12];
#pragma unroll
        for (int r = 0; r < 12; ++r) a[r] = 0.f;

        // prologue: stage chunk 0 into buf 0 (linear layout -> conflict-free writes)
        {
            const float* gw = qkv_w + (size_t)pass * 192 * 256;
            stg0 = *reinterpret_cast<const float4*>(gw + (s0 >> 2) * 256 + (s0 & 3) * 4);
            stg1 = *reinterpret_cast<const float4*>(gw + (s1 >> 2) * 256 + (s1 & 3) * 4);
            stg2 = *reinterpret_cast<const float4*>(gw + (s2 >> 2) * 256 + (s2 & 3) * 4);
            *reinterpret_cast<float4*>(&wt[0][s0 * 4]) = stg0;
            *reinterpret_cast<float4*>(&wt[0][s1 * 4]) = stg1;
            *reinterpret_cast<float4*>(&wt[0][s2 * 4]) = stg2;
        }
        __syncthreads();

        for (int cc = 0; cc < 16; ++cc) {
            const int buf = cc & 1;
            // prefetch next chunk into registers (hidden under compute)
            if (cc < 15) {
                const float* gw = qkv_w + (size_t)pass * 192 * 256 + (cc + 1) * 16;
                stg0 = *reinterpret_cast<const float4*>(gw + (s0 >> 2) * 256 + (s0 & 3) * 4);
                stg1 = *reinterpret_cast<const float4*>(gw + (s1 >> 2) * 256 + (s1 & 3) * 4);
                stg2 = *reinterpret_cast<const float4*>(gw + (s2 >> 2) * 256 + (s2 & 3) * 4);
            }
            // compute this chunk: thread og handles channels {og + 16j}; each
            // channel's chain accumulates over c ascending with the same DOT4
            // statement tree as the baseline -> bit-identical qs.
            // wt row offsets are j*1024B immediates off one base (low addr-VALU).
            const float* xrow = &xs[pix * 260 + cc * 16];
#pragma unroll
            for (int c4 = 0; c4 < 4; ++c4) {
                const float4 xv = *reinterpret_cast<const float4*>(&xrow[c4 * 4]);
                const float* wbase = &wt[buf][og * 16 + c4 * 4];
#pragma unroll
                for (int j = 0; j < 12; ++j) {
                    const float4 wvj = *reinterpret_cast<const float4*>(&wbase[j * 256]);
                    DOT4(a[j], xv, wvj);
                }
            }
            // publish next chunk (other buffer — safe while peers finish this one)
            if (cc < 15) {
                *reinterpret_cast<float4*>(&wt[buf ^ 1][s0 * 4]) = stg0;
                *reinterpret_cast<float4*>(&wt[buf ^ 1][s1 * 4]) = stg1;
                *reinterpret_cast<float4*>(&wt[buf ^ 1][s2 * 4]) = stg2;
            }
            __syncthreads();
        }
        // write qs[ch][pix]  (ch = og + 16j -> 2-way bank alias, free)
#pragma unroll
        for (int j = 0; j < 12; ++j)
            qs[(og + 16 * j) * 16 + pix] = a[j];
        __syncthreads();

        // ---- Phase B2: 5x5 avg-pool (pad 2) within the 4x4 window, 192 ch ----
        if (t < 192) {
            const float4* sr = reinterpret_cast<const float4*>(&qs[t * 16]);
            const float4 r0 = sr[0], r1 = sr[1], r2 = sr[2], r3 = sr[3];
            float col[4], tmp0[4], tmp3[4];
            {
                const float c0 = r0.x + r1.x + r2.x + r3.x;
                const float c1 = r0.y + r1.y + r2.y + r3.y;
                const float c2 = r0.z + r1.z + r2.z + r3.z;
                const float c3 = r0.w + r1.w + r2.w + r3.w;
                col[0] = c0; col[1] = c1; col[2] = c2; col[3] = c3;
                tmp0[0] = c0 - r3.x; tmp0[1] = c1 - r3.y; tmp0[2] = c2 - r3.z; tmp0[3] = c3 - r3.w;
                tmp3[0] = c0 - r0.x; tmp3[1] = c1 - r0.y; tmp3[2] = c2 - r0.z; tmp3[3] = c3 - r0.w;
            }
            float4* pr = reinterpret_cast<float4*>(&qs[(192 + t) * 16]);
            const float k25 = 1.f / 25.f;
#pragma unroll
            for (int i = 0; i < 4; ++i) {
                const float* tr = (i == 0) ? tmp0 : ((i == 3) ? tmp3 : col);
                const float hs = tr[0] + tr[1] + tr[2] + tr[3];
                float4 o;
                o.x = (hs - tr[3]) * k25;
                o.y = hs * k25;
                o.z = hs * k25;
                o.w = (hs - tr[0]) * k25;
                pr[i] = o;
            }
        }
        __syncthreads();

        // ---- Phase C: linear attention (fp32, verbatim), att -> bf16 hi/lo frags ----
        {
            const int grp = t >> 4;        // 0..15 (8 direct + 8 pooled)
            const int l = t & 15;          // pixel
            const int base = (grp < 8) ? (grp * 24 * 16) : ((192 + (grp - 8) * 24) * 16);

            float qd[8], kd[8], vm[8];
#pragma unroll
            for (int d = 0; d < 8; ++d) qd[d] = fmaxf(0.f, qs[base + d * 16 + l]);
#pragma unroll
            for (int d = 0; d < 8; ++d) kd[d] = fmaxf(0.f, qs[base + (8 + d) * 16 + l]);
#pragma unroll
            for (int m = 0; m < 8; ++m) vm[m] = qs[base + (16 + m) * 16 + l];

            float kv[8][9];
#pragma unroll
            for (int d = 0; d < 8; ++d) {
#pragma unroll
                for (int m = 0; m < 8; ++m) kv[d][m] = kd[d] * vm[m];
                kv[d][8] = kd[d];          // v[:,8] == 1 (pad)
            }
#pragma unroll
            for (int off = 1; off <= 8; off <<= 1)
#pragma unroll
                for (int d = 0; d < 8; ++d)
#pragma unroll
                    for (int m = 0; m < 9; ++m)
                        kv[d][m] += __shfl_xor(kv[d][m], off, 64);

            float o8 = 0.f;
#pragma unroll
            for (int d = 0; d < 8; ++d) o8 += qd[d] * kv[d][8];
            const float den = 1.f / (o8 + 1e-15f);

            // att frag layout: elem = (kblk*16 + pix)*8 + j; kblk = grp, j = m
            bf16x8 sh, sl;
#pragma unroll
            for (int m = 0; m < 8; ++m) {
                float om = 0.f;
#pragma unroll
                for (int d = 0; d < 8; ++d) om += qd[d] * kv[d][m];
                const float vvv = om * den;
                const unsigned short h = f2b(vvv);
                sh[m] = (short)h;
                sl[m] = (short)f2b(vvv - b2f(h));
            }
            *reinterpret_cast<bf16x8*>(&af_hi[t * 8]) = sh;
            *reinterpret_cast<bf16x8*>(&af_lo[t * 8]) = sl;
        }
        __syncthreads();

        // ---- Phase D: proj partial GEMM via MFMA.  Wave wv owns oc-tiles wv*4+{0..3} ----
        {
#pragma unroll
            for (int s = 0; s < 4; ++s) {
                const int u = ((s * 4 + lk) * 16 + lrow) * 8;
                const bf16x8 bh = *reinterpret_cast<const bf16x8*>(&af_hi[u]);
                const bf16x8 bl = *reinterpret_cast<const bf16x8*>(&af_lo[u]);
                // local k 0..63 -> direct cols pass*64+k ; 64..127 -> pooled 256+pass*64+(k-64)
                const int colbase = ((s < 2) ? (pass * 64 + s * 32)
                                             : (256 + pass * 64 + (s - 2) * 32)) + lk * 8;
#pragma unroll
                for (int tt = 0; tt < 4; ++tt) {
                    const int row = (wv * 4 + tt) * 16 + lrow;
                    const bf16x8 ah = *reinterpret_cast<const bf16x8*>(wp_h + (size_t)row * 512 + colbase);
                    const bf16x8 al = *reinterpret_cast<const bf16x8*>(wp_l + (size_t)row * 512 + colbase);
                    pacc[tt] = __builtin_amdgcn_mfma_f32_16x16x32_bf16(ah, bh, pacc[tt], 0, 0, 0);
                    pacc[tt] = __builtin_amdgcn_mfma_f32_16x16x32_bf16(ah, bl, pacc[tt], 0, 0, 0);
                    pacc[tt] = __builtin_amdgcn_mfma_f32_16x16x32_bf16(al, bh, pacc[tt], 0, 0, 0);
                }
            }
        }
        __syncthreads();
    }

    // ---- Epilogue: transpose pacc through LDS (qs is free), BN, coalesced stores ----
#pragma unroll
    for (int tt = 0; tt < 4; ++tt) {
        const int c0 = (wv * 4 + tt) * 16 + lk * 4;
#pragma unroll
        for (int r = 0; r < 4; ++r)
            qs[(c0 + r) * 16 + lrow] = pacc[tt][r];
    }
    __syncthreads();
    {
        const int oc = t;
        const float inv = bn_g[oc] * __frsqrt_rn(bn_v[oc] + 1e-5f);
        const float bet2 = bn_b[oc] - bn_m[oc] * inv;
        const float* rowp = &qs[oc * 16];
#pragma unroll
        for (int i = 0; i < 4; ++i) {
            float4 s4;
            s4.x = rowp[i * 4 + 0] * inv + bet2;
            s4.y = rowp[i * 4 + 1] * inv + bet2;
            s4.z = rowp[i * 4 + 2] * inv + bet2;
            s4.w = rowp[i * 4 + 3] * inv + bet2;
            const size_t ea = ((size_t)(b * COUT_ + oc) * H_ + (h0 + i)) * (size_t)W_ + w0;
            *reinterpret_cast<float4*>(y + ea) = s4;    // 16B store, aligned
        }
    }
}

extern "C" void kernel_launch(void* const* d_in, const int* in_sizes, int n_in,
                              void* d_out, int out_size, void* d_ws, size_t ws_size,
                              hipStream_t stream) {
    const float* x      = (const float*)d_in[0];
    const float* qkv_w  = (const float*)d_in[1];
    const float* proj_w = (const float*)d_in[2];
    const float* bn_g   = (const float*)d_in[3];
    const float* bn_b   = (const float*)d_in[4];
    const float* bn_m   = (const float*)d_in[5];
    const float* bn_v   = (const float*)d_in[6];
    float* y = (float*)d_out;

    unsigned short* ws = (unsigned short*)d_ws;   // needs 524,288 B
    prep_weights<<<dim3(512), dim3(256), 0, stream>>>(proj_w, ws);
    wmsa_fused<<<dim3(9216), dim3(256), 0, stream>>>(
        x, qkv_w, ws, ws + PROJ_N,
        bn_g, bn_b, bn_m, bn_v, y);
}

// Round 5
// 2280.210 us; speedup vs baseline: 2.1152x; 1.2311x over previous
//
#include <hip/hip_runtime.h>

#define HN 48
#define WN 48
#define CIN_ 256
#define H_ 192
#define W_ 192
#define COUT_ 256

#define PROJ_N (256 * 512)

#define DOT4(a, xv, wv) a += xv.x*wv.x + xv.y*wv.y + xv.z*wv.z + xv.w*wv.w

typedef __attribute__((ext_vector_type(8))) short bf16x8;   // 8 bf16 (MFMA A/B frag)
typedef __attribute__((ext_vector_type(4))) float f32x4;    // MFMA C/D frag

__device__ __forceinline__ unsigned short f2b(float f) {    // fp32 -> bf16 RNE
    unsigned int u = __float_as_uint(f);
    u = u + 0x7FFFu + ((u >> 16) & 1u);
    return (unsigned short)(u >> 16);
}
__device__ __forceinline__ float b2f(unsigned short h) {
    return __uint_as_float(((unsigned int)h) << 16);
}

// One-time proj weight split: w = hi(bf16) + lo(bf16).  att->proj is not
// relu-amplified; 3-MFMA 2-way split adds only ~1e-5 to y.
__global__ __launch_bounds__(256) void prep_weights(const float* __restrict__ proj_w,
                                                    unsigned short* __restrict__ ws) {
    const int idx = blockIdx.x * 256 + threadIdx.x;
    if (idx < PROJ_N) {
        const float v = proj_w[idx];
        const unsigned short h = f2b(v);
        ws[idx] = h;
        ws[PROJ_N + idx] = f2b(v - b2f(h));
    }
}

// One workgroup (256 threads = 4 waves) per FOUR horizontally-adjacent 4x4
// windows (same b,hn; wn4*4 .. wn4*4+3).  Rationale (round-4 counters): the
// 1-window kernel was stall-bound (VALUBusy 41%, all pipes idle) because each
// 16-col weight chunk gave only ~384 FMA-cycles per barrier.  The weight tile
// is window-independent, so 4 windows/block gives 4x compute per staged chunk
// (12 FMA per LDS read), /4 staging + barrier overhead per window, and proj
// weights loaded once per pass for 4 windows.  LDS 148.5KB -> 1 block/CU;
// latency hides via in-wave ILP (48 independent accumulator chains).
// Phase-B per-channel arithmetic stays BIT-IDENTICAL to the passing round-4
// kernel (same DOT4 tree, c ascending) — the relu in C amplifies qs
// perturbations, so we pin the known-passing draw.
__global__ __launch_bounds__(256, 1)
void wmsa_fused(const float* __restrict__ x, const float* __restrict__ qkv_w,
                const unsigned short* __restrict__ wp_h, const unsigned short* __restrict__ wp_l,
                const float* __restrict__ bn_g, const float* __restrict__ bn_b,
                const float* __restrict__ bn_m, const float* __restrict__ bn_v,
                float* __restrict__ y)
{
    __shared__ __align__(16) float xs[4][4164];           // 66,624 B  x windows (pad: row 260, win +4)
    __shared__ __align__(16) float wt[2][192 * 16];       // 24,576 B  qkv weight chunks (dbuf)
    __shared__ __align__(16) float qs[384 * 16];          // 24,576 B  qkv + pooled (one window)
    __shared__ __align__(16) unsigned short af_hi[4][2048]; // 16,384 B att frags hi (4 windows)
    __shared__ __align__(16) unsigned short af_lo[4][2048]; // 16,384 B att frags lo
                                                          // total 148,544 B -> 1 WG/CU

    const int t = threadIdx.x;
    const int bid = blockIdx.x;
    // XCD swizzle over 2304 blocks (288 per XCD, bijective)
    const int wb = (bid % 288) * 8 + (bid / 288);
    const int b = wb / 576;              // 48 hn * 12 wn4
    const int rem = wb % 576;
    const int hn = rem / 12, wn4 = rem % 12;
    const int h0 = hn * 4, w0 = wn4 * 16;

    // ---- Phase A: load 4 windows (256 ch x 64 pix), 64B-line coalesced ----
#pragma unroll
    for (int k = 0; k < 16; ++k) {
        const int idx = t + k * 256;              // 4096 float4 loads
        const int wq = idx & 3;                   // window 0..3
        const int i = (idx >> 2) & 3;             // row in window
        const int c = idx >> 4;                   // channel
        const size_t ea = ((size_t)(b * CIN_ + c) * H_ + (h0 + i)) * (size_t)W_ + (w0 + wq * 4);
        const float4 r = *reinterpret_cast<const float4*>(x + ea);  // 16B, aligned
        float* xw = xs[wq];
        xw[(i * 4 + 0) * 260 + c] = r.x;
        xw[(i * 4 + 1) * 260 + c] = r.y;
        xw[(i * 4 + 2) * 260 + c] = r.z;
        xw[(i * 4 + 3) * 260 + c] = r.w;
    }

    const int og = t >> 4;       // 0..15
    const int pix = t & 15;      // 0..15
    const int lane = t & 63;
    const int wv = t >> 6;       // wave 0..3
    const int lrow = lane & 15;  // MFMA row/col lane
    const int lk = lane >> 4;    // k-subblock 0..3

    f32x4 pacc[4][4];            // [oc-tile][window], live across all passes
#pragma unroll
    for (int i = 0; i < 4; ++i)
#pragma unroll
        for (int w = 0; w < 4; ++w) pacc[i][w] = (f32x4){0.f, 0.f, 0.f, 0.f};

    // reg-stage slots: 768 float4 slots / 256 threads = 3 each (slot = row*4 + cq)
    const int s0 = t, s1 = t + 256, s2 = t + 512;
    float4 stg0, stg1, stg2;

    __syncthreads();

    for (int pass = 0; pass < 4; ++pass) {
        // ---- Phase B: qkv GEMM, fp32 VALU, 4 windows per staged chunk ----
        float a[4][12];          // [window][channel j]
#pragma unroll
        for (int w = 0; w < 4; ++w)
#pragma unroll
            for (int j = 0; j < 12; ++j) a[w][j] = 0.f;

        {   // prologue: stage chunk 0 into buf 0
            const float* gw = qkv_w + (size_t)pass * 192 * 256;
            stg0 = *reinterpret_cast<const float4*>(gw + (s0 >> 2) * 256 + (s0 & 3) * 4);
            stg1 = *reinterpret_cast<const float4*>(gw + (s1 >> 2) * 256 + (s1 & 3) * 4);
            stg2 = *reinterpret_cast<const float4*>(gw + (s2 >> 2) * 256 + (s2 & 3) * 4);
            *reinterpret_cast<float4*>(&wt[0][s0 * 4]) = stg0;
            *reinterpret_cast<float4*>(&wt[0][s1 * 4]) = stg1;
            *reinterpret_cast<float4*>(&wt[0][s2 * 4]) = stg2;
        }
        __syncthreads();

        for (int cc = 0; cc < 16; ++cc) {
            const int buf = cc & 1;
            if (cc < 15) {       // prefetch next chunk into registers
                const float* gw = qkv_w + (size_t)pass * 192 * 256 + (cc + 1) * 16;
                stg0 = *reinterpret_cast<const float4*>(gw + (s0 >> 2) * 256 + (s0 & 3) * 4);
                stg1 = *reinterpret_cast<const float4*>(gw + (s1 >> 2) * 256 + (s1 & 3) * 4);
                stg2 = *reinterpret_cast<const float4*>(gw + (s2 >> 2) * 256 + (s2 & 3) * 4);
            }
            // each wvj read once, feeds 4 windows (12 FMA per LDS read);
            // per-channel chain over c ascending = round-4 statement tree
            const int xoff = pix * 260 + cc * 16;
#pragma unroll
            for (int c4 = 0; c4 < 4; ++c4) {
                const float4 xv0 = *reinterpret_cast<const float4*>(&xs[0][xoff + c4 * 4]);
                const float4 xv1 = *reinterpret_cast<const float4*>(&xs[1][xoff + c4 * 4]);
                const float4 xv2 = *reinterpret_cast<const float4*>(&xs[2][xoff + c4 * 4]);
                const float4 xv3 = *reinterpret_cast<const float4*>(&xs[3][xoff + c4 * 4]);
                const float* wbase = &wt[buf][og * 16 + c4 * 4];
#pragma unroll
                for (int j = 0; j < 12; ++j) {
                    const float4 wvj = *reinterpret_cast<const float4*>(&wbase[j * 256]);
                    DOT4(a[0][j], xv0, wvj);
                    DOT4(a[1][j], xv1, wvj);
                    DOT4(a[2][j], xv2, wvj);
                    DOT4(a[3][j], xv3, wvj);
                }
            }
            if (cc < 15) {       // publish next chunk into other buffer
                *reinterpret_cast<float4*>(&wt[buf ^ 1][s0 * 4]) = stg0;
                *reinterpret_cast<float4*>(&wt[buf ^ 1][s1 * 4]) = stg1;
                *reinterpret_cast<float4*>(&wt[buf ^ 1][s2 * 4]) = stg2;
            }
            __syncthreads();
        }

        // ---- per-window: qs write, B2 pool, C attention -> af[w] ----
#pragma unroll
        for (int w = 0; w < 4; ++w) {
            // write qs[ch][pix] (ch = og + 16j -> 2-way bank alias, free)
#pragma unroll
            for (int j = 0; j < 12; ++j)
                qs[(og + 16 * j) * 16 + pix] = a[w][j];
            __syncthreads();

            // ---- Phase B2: 5x5 avg-pool (pad 2) within the 4x4 window ----
            if (t < 192) {
                const float4* sr = reinterpret_cast<const float4*>(&qs[t * 16]);
                const float4 r0 = sr[0], r1 = sr[1], r2 = sr[2], r3 = sr[3];
                float col[4], tmp0[4], tmp3[4];
                {
                    const float c0 = r0.x + r1.x + r2.x + r3.x;
                    const float c1 = r0.y + r1.y + r2.y + r3.y;
                    const float c2 = r0.z + r1.z + r2.z + r3.z;
                    const float c3 = r0.w + r1.w + r2.w + r3.w;
                    col[0] = c0; col[1] = c1; col[2] = c2; col[3] = c3;
                    tmp0[0] = c0 - r3.x; tmp0[1] = c1 - r3.y; tmp0[2] = c2 - r3.z; tmp0[3] = c3 - r3.w;
                    tmp3[0] = c0 - r0.x; tmp3[1] = c1 - r0.y; tmp3[2] = c2 - r0.z; tmp3[3] = c3 - r0.w;
                }
                float4* pr = reinterpret_cast<float4*>(&qs[(192 + t) * 16]);
                const float k25 = 1.f / 25.f;
#pragma unroll
                for (int i = 0; i < 4; ++i) {
                    const float* tr = (i == 0) ? tmp0 : ((i == 3) ? tmp3 : col);
                    const float hs = tr[0] + tr[1] + tr[2] + tr[3];
                    float4 o;
                    o.x = (hs - tr[3]) * k25;
                    o.y = hs * k25;
                    o.z = hs * k25;
                    o.w = (hs - tr[0]) * k25;
                    pr[i] = o;
                }
            }
            __syncthreads();

            // ---- Phase C: linear attention (fp32, verbatim) -> af[w] ----
            {
                const int grp = t >> 4;        // 0..15 (8 direct + 8 pooled)
                const int l = t & 15;          // pixel
                const int base = (grp < 8) ? (grp * 24 * 16) : ((192 + (grp - 8) * 24) * 16);

                float qd[8], kd[8], vm[8];
#pragma unroll
                for (int d = 0; d < 8; ++d) qd[d] = fmaxf(0.f, qs[base + d * 16 + l]);
#pragma unroll
                for (int d = 0; d < 8; ++d) kd[d] = fmaxf(0.f, qs[base + (8 + d) * 16 + l]);
#pragma unroll
                for (int m = 0; m < 8; ++m) vm[m] = qs[base + (16 + m) * 16 + l];

                float kv[8][9];
#pragma unroll
                for (int d = 0; d < 8; ++d) {
#pragma unroll
                    for (int m = 0; m < 8; ++m) kv[d][m] = kd[d] * vm[m];
                    kv[d][8] = kd[d];          // v[:,8] == 1 (pad)
                }
#pragma unroll
                for (int off = 1; off <= 8; off <<= 1)
#pragma unroll
                    for (int d = 0; d < 8; ++d)
#pragma unroll
                        for (int m = 0; m < 9; ++m)
                            kv[d][m] += __shfl_xor(kv[d][m], off, 64);

                float o8 = 0.f;
#pragma unroll
                for (int d = 0; d < 8; ++d) o8 += qd[d] * kv[d][8];
                const float den = 1.f / (o8 + 1e-15f);

                bf16x8 sh, sl;
#pragma unroll
                for (int m = 0; m < 8; ++m) {
                    float om = 0.f;
#pragma unroll
                    for (int d = 0; d < 8; ++d) om += qd[d] * kv[d][m];
                    const float vvv = om * den;
                    const unsigned short h = f2b(vvv);
                    sh[m] = (short)h;
                    sl[m] = (short)f2b(vvv - b2f(h));
                }
                *reinterpret_cast<bf16x8*>(&af_hi[w][t * 8]) = sh;
                *reinterpret_cast<bf16x8*>(&af_lo[w][t * 8]) = sl;
            }
            __syncthreads();
        }

        // ---- Phase D: proj partial GEMM via MFMA, weights loaded once for 4 windows ----
#pragma unroll
        for (int s = 0; s < 4; ++s) {
            const int u = ((s * 4 + lk) * 16 + lrow) * 8;
            const bf16x8 bh0 = *reinterpret_cast<const bf16x8*>(&af_hi[0][u]);
            const bf16x8 bh1 = *reinterpret_cast<const bf16x8*>(&af_hi[1][u]);
            const bf16x8 bh2 = *reinterpret_cast<const bf16x8*>(&af_hi[2][u]);
            const bf16x8 bh3 = *reinterpret_cast<const bf16x8*>(&af_hi[3][u]);
            const bf16x8 bl0 = *reinterpret_cast<const bf16x8*>(&af_lo[0][u]);
            const bf16x8 bl1 = *reinterpret_cast<const bf16x8*>(&af_lo[1][u]);
            const bf16x8 bl2 = *reinterpret_cast<const bf16x8*>(&af_lo[2][u]);
            const bf16x8 bl3 = *reinterpret_cast<const bf16x8*>(&af_lo[3][u]);
            // local k 0..63 -> direct cols pass*64+k ; 64..127 -> pooled 256+pass*64+(k-64)
            const int colbase = ((s < 2) ? (pass * 64 + s * 32)
                                         : (256 + pass * 64 + (s - 2) * 32)) + lk * 8;
#pragma unroll
            for (int tt = 0; tt < 4; ++tt) {
                const int row = (wv * 4 + tt) * 16 + lrow;
                const bf16x8 ah = *reinterpret_cast<const bf16x8*>(wp_h + (size_t)row * 512 + colbase);
                const bf16x8 al = *reinterpret_cast<const bf16x8*>(wp_l + (size_t)row * 512 + colbase);
                pacc[tt][0] = __builtin_amdgcn_mfma_f32_16x16x32_bf16(ah, bh0, pacc[tt][0], 0, 0, 0);
                pacc[tt][0] = __builtin_amdgcn_mfma_f32_16x16x32_bf16(ah, bl0, pacc[tt][0], 0, 0, 0);
                pacc[tt][0] = __builtin_amdgcn_mfma_f32_16x16x32_bf16(al, bh0, pacc[tt][0], 0, 0, 0);
                pacc[tt][1] = __builtin_amdgcn_mfma_f32_16x16x32_bf16(ah, bh1, pacc[tt][1], 0, 0, 0);
                pacc[tt][1] = __builtin_amdgcn_mfma_f32_16x16x32_bf16(ah, bl1, pacc[tt][1], 0, 0, 0);
                pacc[tt][1] = __builtin_amdgcn_mfma_f32_16x16x32_bf16(al, bh1, pacc[tt][1], 0, 0, 0);
                pacc[tt][2] = __builtin_amdgcn_mfma_f32_16x16x32_bf16(ah, bh2, pacc[tt][2], 0, 0, 0);
                pacc[tt][2] = __builtin_amdgcn_mfma_f32_16x16x32_bf16(ah, bl2, pacc[tt][2], 0, 0, 0);
                pacc[tt][2] = __builtin_amdgcn_mfma_f32_16x16x32_bf16(al, bh2, pacc[tt][2], 0, 0, 0);
                pacc[tt][3] = __builtin_amdgcn_mfma_f32_16x16x32_bf16(ah, bh3, pacc[tt][3], 0, 0, 0);
                pacc[tt][3] = __builtin_amdgcn_mfma_f32_16x16x32_bf16(ah, bl3, pacc[tt][3], 0, 0, 0);
                pacc[tt][3] = __builtin_amdgcn_mfma_f32_16x16x32_bf16(al, bh3, pacc[tt][3], 0, 0, 0);
            }
        }
        // no barrier needed: af/qs/wt hazards are covered by next pass's chunk barriers
    }

    // ---- Epilogue: per window, transpose pacc through qs, BN, coalesced stores ----
    const int oc = t;
    const float inv = bn_g[oc] * __frsqrt_rn(bn_v[oc] + 1e-5f);
    const float bet2 = bn_b[oc] - bn_m[oc] * inv;
#pragma unroll
    for (int w = 0; w < 4; ++w) {
        __syncthreads();
#pragma unroll
        for (int tt = 0; tt < 4; ++tt) {
            const int c0 = (wv * 4 + tt) * 16 + lk * 4;
#pragma unroll
            for (int r = 0; r < 4; ++r)
                qs[(c0 + r) * 16 + lrow] = pacc[tt][w][r];
        }
        __syncthreads();
        const float* rowp = &qs[oc * 16];
#pragma unroll
        for (int i = 0; i < 4; ++i) {
            float4 s4;
            s4.x = rowp[i * 4 + 0] * inv + bet2;
            s4.y = rowp[i * 4 + 1] * inv + bet2;
            s4.z = rowp[i * 4 + 2] * inv + bet2;
            s4.w = rowp[i * 4 + 3] * inv + bet2;
            const size_t ea = ((size_t)(b * COUT_ + oc) * H_ + (h0 + i)) * (size_t)W_ + (w0 + w * 4);
            *reinterpret_cast<float4*>(y + ea) = s4;    // 16B store, aligned
        }
    }
}

extern "C" void kernel_launch(void* const* d_in, const int* in_sizes, int n_in,
                              void* d_out, int out_size, void* d_ws, size_t ws_size,
                              hipStream_t stream) {
    const float* x      = (const float*)d_in[0];
    const float* qkv_w  = (const float*)d_in[1];
    const float* proj_w = (const float*)d_in[2];
    const float* bn_g   = (const float*)d_in[3];
    const float* bn_b   = (const float*)d_in[4];
    const float* bn_m   = (const float*)d_in[5];
    const float* bn_v   = (const float*)d_in[6];
    float* y = (float*)d_out;

    unsigned short* ws = (unsigned short*)d_ws;   // needs 524,288 B
    prep_weights<<<dim3(512), dim3(256), 0, stream>>>(proj_w, ws);
    wmsa_fused<<<dim3(2304), dim3(256), 0, stream>>>(
        x, qkv_w, ws, ws + PROJ_N,
        bn_g, bn_b, bn_m, bn_v, y);
}

// Round 7
// 2116.099 us; speedup vs baseline: 2.2793x; 1.0776x over previous
//
#include <hip/hip_runtime.h>

#define HN 48
#define WN 48
#define CIN_ 256
#define H_ 192
#define W_ 192
#define COUT_ 256

#define PROJ_N (256 * 512)

#define DOT4(a, xv, wv) a += xv.x*wv.x + xv.y*wv.y + xv.z*wv.z + xv.w*wv.w

typedef __attribute__((ext_vector_type(8))) short bf16x8;   // 8 bf16 (MFMA A/B frag)
typedef __attribute__((ext_vector_type(4))) float f32x4;    // MFMA C/D frag

__device__ __forceinline__ unsigned short f2b(float f) {    // fp32 -> bf16 RNE
    unsigned int u = __float_as_uint(f);
    u = u + 0x7FFFu + ((u >> 16) & 1u);
    return (unsigned short)(u >> 16);
}
__device__ __forceinline__ float b2f(unsigned short h) {
    return __uint_as_float(((unsigned int)h) << 16);
}

// One-time proj weight split: w = hi(bf16) + lo(bf16).  att->proj is not
// relu-amplified; 3-MFMA 2-way split adds only ~1e-5 to y.
__global__ __launch_bounds__(256) void prep_weights(const float* __restrict__ proj_w,
                                                    unsigned short* __restrict__ ws) {
    const int idx = blockIdx.x * 256 + threadIdx.x;
    if (idx < PROJ_N) {
        const float v = proj_w[idx];
        const unsigned short h = f2b(v);
        ws[idx] = h;
        ws[PROJ_N + idx] = f2b(v - b2f(h));
    }
}

// 512 threads (8 waves) per FOUR horizontally-adjacent 4x4 windows.
// Round-5 counters (VALUBusy 39.5%, 1 wave/SIMD, no pipe >50%) showed pure
// latency/serialization stall.  This version keeps the identical arithmetic
// (bit-identical y vs round 5) but runs 8 waves -> 2 waves/SIMD for latency
// hiding, and processes B2/C for TWO windows concurrently (waves 0-3 handle
// window 2p, waves 4-7 handle 2p+1), halving the serial attention section.
//   B : each thread owns 6 channels (og2 + 32j); same DOT4 tree over
//       ascending c -> qs bit-identical to the passing round-5 kernel.
//   D : window-pair batched MFMA, same per-accumulator MFMA order.
// (Round 6 was an infra failure — "container failed twice", no kernel signal —
//  so this is a resubmission of the audited round-6 source.)
__global__ __launch_bounds__(512, 2)
void wmsa_fused(const float* __restrict__ x, const float* __restrict__ qkv_w,
                const unsigned short* __restrict__ wp_h, const unsigned short* __restrict__ wp_l,
                const float* __restrict__ bn_g, const float* __restrict__ bn_b,
                const float* __restrict__ bn_m, const float* __restrict__ bn_v,
                float* __restrict__ y)
{
    __shared__ __align__(16) float xs[4][4164];             // 66,624 B  x windows
    __shared__ __align__(16) float wt[2][3072];             // 24,576 B  qkv weight chunks (dbuf)
    __shared__ __align__(16) float qs[2][6144];             // 49,152 B  qkv+pooled (2 windows)
    __shared__ __align__(16) unsigned short af_hi[2][2048]; //  8,192 B  att frags hi (pair)
    __shared__ __align__(16) unsigned short af_lo[2][2048]; //  8,192 B  att frags lo (pair)
                                                            // total 156,736 B -> 1 WG/CU

    const int t = threadIdx.x;
    const int bid = blockIdx.x;
    // XCD swizzle over 2304 blocks (288 per XCD, bijective)
    const int wb = (bid % 288) * 8 + (bid / 288);
    const int b = wb / 576;              // 48 hn * 12 wn4
    const int rem = wb % 576;
    const int hn = rem / 12, wn4 = rem % 12;
    const int h0 = hn * 4, w0 = wn4 * 16;

    // ---- Phase A: load 4 windows (256 ch x 64 pix) ----
#pragma unroll
    for (int k = 0; k < 8; ++k) {
        const int idx = t + k * 512;              // 4096 float4 loads
        const int wq = idx & 3;                   // window 0..3
        const int i = (idx >> 2) & 3;             // row in window
        const int c = idx >> 4;                   // channel
        const size_t ea = ((size_t)(b * CIN_ + c) * H_ + (h0 + i)) * (size_t)W_ + (w0 + wq * 4);
        const float4 r = *reinterpret_cast<const float4*>(x + ea);  // 16B, aligned
        float* xw = xs[wq];
        xw[(i * 4 + 0) * 260 + c] = r.x;
        xw[(i * 4 + 1) * 260 + c] = r.y;
        xw[(i * 4 + 2) * 260 + c] = r.z;
        xw[(i * 4 + 3) * 260 + c] = r.w;
    }

    const int og2 = t >> 4;      // 0..31 (channel group)
    const int pix = t & 15;      // 0..15
    const int lane = t & 63;
    const int wv = t >> 6;       // wave 0..7
    const int lrow = lane & 15;  // MFMA row/col lane
    const int lk = lane >> 4;    // k-subblock 0..3
    const int wsel = t >> 8;     // half 0..1 (wave-uniform)
    const int th = t & 255;      // index within half

    f32x4 pacc[2][4];            // [oc-tile][window], live across all passes
#pragma unroll
    for (int i = 0; i < 2; ++i)
#pragma unroll
        for (int w = 0; w < 4; ++w) pacc[i][w] = (f32x4){0.f, 0.f, 0.f, 0.f};

    // wt staging: 768 float4 slots; slot t for all, slot 512+t for t<256
    const int s0 = t, s1 = 512 + t;
    float4 stg0, stg1;

    __syncthreads();

    for (int pass = 0; pass < 4; ++pass) {
        // ---- Phase B: qkv GEMM, fp32 VALU, 4 windows per staged chunk ----
        float a[4][6];           // [window][channel j], ch = og2 + 32j
#pragma unroll
        for (int w = 0; w < 4; ++w)
#pragma unroll
            for (int j = 0; j < 6; ++j) a[w][j] = 0.f;

        {   // prologue: stage chunk 0 into buf 0
            const float* gw = qkv_w + (size_t)pass * 192 * 256;
            stg0 = *reinterpret_cast<const float4*>(gw + (s0 >> 2) * 256 + (s0 & 3) * 4);
            if (t < 256) stg1 = *reinterpret_cast<const float4*>(gw + (s1 >> 2) * 256 + (s1 & 3) * 4);
            *reinterpret_cast<float4*>(&wt[0][s0 * 4]) = stg0;
            if (t < 256) *reinterpret_cast<float4*>(&wt[0][s1 * 4]) = stg1;
        }
        __syncthreads();

        for (int cc = 0; cc < 16; ++cc) {
            const int buf = cc & 1;
            if (cc < 15) {       // prefetch next chunk into registers
                const float* gw = qkv_w + (size_t)pass * 192 * 256 + (cc + 1) * 16;
                stg0 = *reinterpret_cast<const float4*>(gw + (s0 >> 2) * 256 + (s0 & 3) * 4);
                if (t < 256) stg1 = *reinterpret_cast<const float4*>(gw + (s1 >> 2) * 256 + (s1 & 3) * 4);
            }
            // per-channel chain over c ascending = round-5 statement tree
            const int xoff = pix * 260 + cc * 16;
#pragma unroll
            for (int c4 = 0; c4 < 4; ++c4) {
                const float4 xv0 = *reinterpret_cast<const float4*>(&xs[0][xoff + c4 * 4]);
                const float4 xv1 = *reinterpret_cast<const float4*>(&xs[1][xoff + c4 * 4]);
                const float4 xv2 = *reinterpret_cast<const float4*>(&xs[2][xoff + c4 * 4]);
                const float4 xv3 = *reinterpret_cast<const float4*>(&xs[3][xoff + c4 * 4]);
                const float* wbase = &wt[buf][og2 * 16 + c4 * 4];
#pragma unroll
                for (int j = 0; j < 6; ++j) {
                    const float4 wvj = *reinterpret_cast<const float4*>(&wbase[j * 512]);
                    DOT4(a[0][j], xv0, wvj);
                    DOT4(a[1][j], xv1, wvj);
                    DOT4(a[2][j], xv2, wvj);
                    DOT4(a[3][j], xv3, wvj);
                }
            }
            if (cc < 15) {       // publish next chunk into other buffer
                *reinterpret_cast<float4*>(&wt[buf ^ 1][s0 * 4]) = stg0;
                if (t < 256) *reinterpret_cast<float4*>(&wt[buf ^ 1][s1 * 4]) = stg1;
            }
            __syncthreads();
        }

        // ---- window pairs: {0,1} then {2,3}; B2/C run 2 windows concurrently ----
#pragma unroll
        for (int p = 0; p < 2; ++p) {
            // qs write for both windows of the pair (ch = og2+32j -> 2-way, free)
#pragma unroll
            for (int j = 0; j < 6; ++j) {
                qs[0][(og2 + 32 * j) * 16 + pix] = a[2 * p + 0][j];
                qs[1][(og2 + 32 * j) * 16 + pix] = a[2 * p + 1][j];
            }
            __syncthreads();

            // ---- Phase B2: 5x5 avg-pool (pad 2); waves 0-3 -> qs[0], 4-7 -> qs[1] ----
            if (th < 192) {
                float* qsw = qs[wsel];
                const float4* sr = reinterpret_cast<const float4*>(&qsw[th * 16]);
                const float4 r0 = sr[0], r1 = sr[1], r2 = sr[2], r3 = sr[3];
                float col[4], tmp0[4], tmp3[4];
                {
                    const float c0 = r0.x + r1.x + r2.x + r3.x;
                    const float c1 = r0.y + r1.y + r2.y + r3.y;
                    const float c2 = r0.z + r1.z + r2.z + r3.z;
                    const float c3 = r0.w + r1.w + r2.w + r3.w;
                    col[0] = c0; col[1] = c1; col[2] = c2; col[3] = c3;
                    tmp0[0] = c0 - r3.x; tmp0[1] = c1 - r3.y; tmp0[2] = c2 - r3.z; tmp0[3] = c3 - r3.w;
                    tmp3[0] = c0 - r0.x; tmp3[1] = c1 - r0.y; tmp3[2] = c2 - r0.z; tmp3[3] = c3 - r0.w;
                }
                float4* pr = reinterpret_cast<float4*>(&qsw[(192 + th) * 16]);
                const float k25 = 1.f / 25.f;
#pragma unroll
                for (int i = 0; i < 4; ++i) {
                    const float* tr = (i == 0) ? tmp0 : ((i == 3) ? tmp3 : col);
                    const float hs = tr[0] + tr[1] + tr[2] + tr[3];
                    float4 o;
                    o.x = (hs - tr[3]) * k25;
                    o.y = hs * k25;
                    o.z = hs * k25;
                    o.w = (hs - tr[0]) * k25;
                    pr[i] = o;
                }
            }
            __syncthreads();

            // ---- Phase C: linear attention (fp32, verbatim), 2 windows concurrently ----
            {
                const int grp = th >> 4;       // 0..15 (8 direct + 8 pooled)
                const int l = th & 15;         // pixel
                const float* qsw = qs[wsel];
                const int base = (grp < 8) ? (grp * 24 * 16) : ((192 + (grp - 8) * 24) * 16);

                float qd[8], kd[8], vm[8];
#pragma unroll
                for (int d = 0; d < 8; ++d) qd[d] = fmaxf(0.f, qsw[base + d * 16 + l]);
#pragma unroll
                for (int d = 0; d < 8; ++d) kd[d] = fmaxf(0.f, qsw[base + (8 + d) * 16 + l]);
#pragma unroll
                for (int m = 0; m < 8; ++m) vm[m] = qsw[base + (16 + m) * 16 + l];

                float kv[8][9];
#pragma unroll
                for (int d = 0; d < 8; ++d) {
#pragma unroll
                    for (int m = 0; m < 8; ++m) kv[d][m] = kd[d] * vm[m];
                    kv[d][8] = kd[d];          // v[:,8] == 1 (pad)
                }
#pragma unroll
                for (int off = 1; off <= 8; off <<= 1)
#pragma unroll
                    for (int d = 0; d < 8; ++d)
#pragma unroll
                        for (int m = 0; m < 9; ++m)
                            kv[d][m] += __shfl_xor(kv[d][m], off, 64);

                float o8 = 0.f;
#pragma unroll
                for (int d = 0; d < 8; ++d) o8 += qd[d] * kv[d][8];
                const float den = 1.f / (o8 + 1e-15f);

                bf16x8 sh, sl;
#pragma unroll
                for (int m = 0; m < 8; ++m) {
                    float om = 0.f;
#pragma unroll
                    for (int d = 0; d < 8; ++d) om += qd[d] * kv[d][m];
                    const float vvv = om * den;
                    const unsigned short h = f2b(vvv);
                    sh[m] = (short)h;
                    sl[m] = (short)f2b(vvv - b2f(h));
                }
                *reinterpret_cast<bf16x8*>(&af_hi[wsel][th * 8]) = sh;
                *reinterpret_cast<bf16x8*>(&af_lo[wsel][th * 8]) = sl;
            }
            __syncthreads();

            // ---- Phase D: proj partial GEMM via MFMA, pair-batched.
            //      Wave wv owns oc-tiles wv*2+{0,1}.  Same per-accumulator MFMA
            //      order as round 5 (hh, hl, lh per s) -> bit-identical y. ----
#pragma unroll
            for (int s = 0; s < 4; ++s) {
                const int u = ((s * 4 + lk) * 16 + lrow) * 8;
                const bf16x8 bh0 = *reinterpret_cast<const bf16x8*>(&af_hi[0][u]);
                const bf16x8 bl0 = *reinterpret_cast<const bf16x8*>(&af_lo[0][u]);
                const bf16x8 bh1 = *reinterpret_cast<const bf16x8*>(&af_hi[1][u]);
                const bf16x8 bl1 = *reinterpret_cast<const bf16x8*>(&af_lo[1][u]);
                // local k 0..63 -> direct cols pass*64+k ; 64..127 -> pooled 256+pass*64+(k-64)
                const int colbase = ((s < 2) ? (pass * 64 + s * 32)
                                             : (256 + pass * 64 + (s - 2) * 32)) + lk * 8;
#pragma unroll
                for (int tt = 0; tt < 2; ++tt) {
                    const int row = (wv * 2 + tt) * 16 + lrow;
                    const bf16x8 ah = *reinterpret_cast<const bf16x8*>(wp_h + (size_t)row * 512 + colbase);
                    const bf16x8 al = *reinterpret_cast<const bf16x8*>(wp_l + (size_t)row * 512 + colbase);
                    pacc[tt][2*p+0] = __builtin_amdgcn_mfma_f32_16x16x32_bf16(ah, bh0, pacc[tt][2*p+0], 0, 0, 0);
                    pacc[tt][2*p+0] = __builtin_amdgcn_mfma_f32_16x16x32_bf16(ah, bl0, pacc[tt][2*p+0], 0, 0, 0);
                    pacc[tt][2*p+0] = __builtin_amdgcn_mfma_f32_16x16x32_bf16(al, bh0, pacc[tt][2*p+0], 0, 0, 0);
                    pacc[tt][2*p+1] = __builtin_amdgcn_mfma_f32_16x16x32_bf16(ah, bh1, pacc[tt][2*p+1], 0, 0, 0);
                    pacc[tt][2*p+1] = __builtin_amdgcn_mfma_f32_16x16x32_bf16(ah, bl1, pacc[tt][2*p+1], 0, 0, 0);
                    pacc[tt][2*p+1] = __builtin_amdgcn_mfma_f32_16x16x32_bf16(al, bh1, pacc[tt][2*p+1], 0, 0, 0);
                }
            }
            // no barrier: next p's qs-write hazard vs this p's C-reads is covered
            // by the bar before D (all waves passed it = all C reads done);
            // D reads af only, next qs-write touches qs only.
        }
    }

    // ---- Epilogue: per pair, transpose pacc through qs, BN, coalesced stores ----
    const int oc = th;
    const float inv = bn_g[oc] * __frsqrt_rn(bn_v[oc] + 1e-5f);
    const float bet2 = bn_b[oc] - bn_m[oc] * inv;
#pragma unroll
    for (int p = 0; p < 2; ++p) {
        __syncthreads();
#pragma unroll
        for (int tt = 0; tt < 2; ++tt) {
            const int c0 = (wv * 2 + tt) * 16 + lk * 4;
#pragma unroll
            for (int r = 0; r < 4; ++r) {
                qs[0][(c0 + r) * 16 + lrow] = pacc[tt][2 * p + 0][r];
                qs[1][(c0 + r) * 16 + lrow] = pacc[tt][2 * p + 1][r];
            }
        }
        __syncthreads();
        const float* rowp = &qs[wsel][oc * 16];
        const int wwin = 2 * p + wsel;
#pragma unroll
        for (int i = 0; i < 4; ++i) {
            float4 s4;
            s4.x = rowp[i * 4 + 0] * inv + bet2;
            s4.y = rowp[i * 4 + 1] * inv + bet2;
            s4.z = rowp[i * 4 + 2] * inv + bet2;
            s4.w = rowp[i * 4 + 3] * inv + bet2;
            const size_t ea = ((size_t)(b * COUT_ + oc) * H_ + (h0 + i)) * (size_t)W_ + (w0 + wwin * 4);
            *reinterpret_cast<float4*>(y + ea) = s4;    // 16B store, aligned
        }
    }
}

extern "C" void kernel_launch(void* const* d_in, const int* in_sizes, int n_in,
                              void* d_out, int out_size, void* d_ws, size_t ws_size,
                              hipStream_t stream) {
    const float* x      = (const float*)d_in[0];
    const float* qkv_w  = (const float*)d_in[1];
    const float* proj_w = (const float*)d_in[2];
    const float* bn_g   = (const float*)d_in[3];
    const float* bn_b   = (const float*)d_in[4];
    const float* bn_m   = (const float*)d_in[5];
    const float* bn_v   = (const float*)d_in[6];
    float* y = (float*)d_out;

    unsigned short* ws = (unsigned short*)d_ws;   // needs 524,288 B
    prep_weights<<<dim3(512), dim3(256), 0, stream>>>(proj_w, ws);
    wmsa_fused<<<dim3(2304), dim3(512), 0, stream>>>(
        x, qkv_w, ws, ws + PROJ_N,
        bn_g, bn_b, bn_m, bn_v, y);
}